// Round 9
// baseline (104.402 us; speedup 1.0000x reference)
//
#include <hip/hip_runtime.h>

// R9 ATTRIBUTION PROBE: identical R8 kernel launched TWICE (idempotent —
// second pass rewrites identical values). dur_us(R9) - dur_us(R8) isolates
// one kernel dispatch's true cost, which the top-5 display (all ~42us ws
// fills) hides. Pre-committed read: delta>=20us -> optimize kernel further;
// delta~11-15us -> kernel is at write-BW floor, revert & declare roofline.

#define VOCAB 3875      // 5^3 + 5^4 + 5^5 (also: float4s per 4-row block)
#define SEQ   512
#define G3    (SEQ - 2) // 510
#define G4    (SEQ - 3) // 509
#define G5    (SEQ - 4) // 508
#define OFF4  125
#define OFF5  750       // 125 + 625
#define NT    512       // threads per block (8 waves)
#define RPB   4         // rows per block
#define BMS   128       // bitmap stride in words (122 used, padded)

typedef float floatx4 __attribute__((ext_vector_type(4)));

__global__ __launch_bounds__(NT) void ngram_bitmap4_kernel(
        const int* __restrict__ tokens,
        float* __restrict__ out) {
    __shared__ __align__(16) int tok[RPB * SEQ];       // 8 KB
    __shared__ unsigned int bm[RPB * BMS];             // 2 KB

    const int b   = blockIdx.x;
    const int tid = threadIdx.x;

    // --- stage 4 rows of tokens (1 int4/lane, coalesced) + zero bitmaps ---
    const int4* tsrc = (const int4*)(tokens + (size_t)b * (RPB * SEQ));
    ((int4*)tok)[tid] = tsrc[tid];                     // 512 * int4 = 2048 ints
    bm[tid] = 0u;                                      // RPB*BMS = 512 words
    __syncthreads();

    // --- scatter: 128 threads per row, 4 windows each, chained base-5 codes ---
    {
        const int row  = tid >> 7;                     // 0..3
        const int lane = tid & 127;
        const int* tr = tok + row * SEQ;
        unsigned int* bmr = bm + row * BMS;
        for (int i = lane; i < G3; i += 128) {
            const int r3 = tr[i] * 25 + tr[i + 1] * 5 + tr[i + 2];
            atomicOr(&bmr[r3 >> 5], 1u << (r3 & 31));
            if (i < G4) {
                const int r4 = r3 * 5 + tr[i + 3];
                const int v4 = OFF4 + r4;
                atomicOr(&bmr[v4 >> 5], 1u << (v4 & 31));
                if (i < G5) {
                    const int v5 = OFF5 + r4 * 5 + tr[i + 4];
                    atomicOr(&bmr[v5 >> 5], 1u << (v5 & 31));
                }
            }
        }
    }
    __syncthreads();

    // --- expand: 4*3875 dwords = exactly 3875 aligned float4 per block ---
    floatx4* ov = (floatx4*)(out + (size_t)b * (RPB * VOCAB));
    #pragma unroll 2
    for (int v = tid; v < VOCAB; v += NT) {
        floatx4 f;
        #pragma unroll
        for (int j = 0; j < 4; ++j) {
            const int d = 4 * v + j;
            const int r = d / VOCAB;                   // magic-mul, constant
            const int c = d - r * VOCAB;
            const unsigned int w = bm[r * BMS + (c >> 5)];
            f[j] = (float)((w >> (c & 31)) & 1u);
        }
        ov[v] = f;
    }
}

extern "C" void kernel_launch(void* const* d_in, const int* in_sizes, int n_in,
                              void* d_out, int out_size, void* d_ws, size_t ws_size,
                              hipStream_t stream) {
    const int* tokens = (const int*)d_in[0];
    float*     out    = (float*)d_out;

    const int B = in_sizes[0] / SEQ;                   // 4096
    // PROBE: two identical launches; delta vs R8 = one kernel's dispatch cost.
    ngram_bitmap4_kernel<<<B / RPB, NT, 0, stream>>>(tokens, out);
    ngram_bitmap4_kernel<<<B / RPB, NT, 0, stream>>>(tokens, out);
}

// Round 10
// 89.864 us; speedup vs baseline: 1.1618x; 1.1618x over previous
//
#include <hip/hip_runtime.h>

// CharNGramVectorizer: per-row binary presence over base-5 n-gram codes
// (n=3,4,5), vocab 3875. Output is exactly {0,1}: build a 3875-bit LDS bitmap
// per row (ds_or scatter), expand to an aligned float4 store stream.
// R9 probe attribution: one dispatch of this kernel = ~13 us vs ~11-13 us
// write-BW floor (63.5 MB out @ 6.3 TB/s + L2-hot reads). The remaining
// ~78 us of dur_us is fixed harness reset traffic (256 MiB ws poison = 42 us,
// out poison, input restores) outside kernel_launch's control.
// RPB=4: block's output region = 62000 B = 3875 aligned float4 (15500 B rows
// are only 4B-aligned individually); grid 1024 = exactly 4 blocks/CU.

#define VOCAB 3875      // 5^3 + 5^4 + 5^5 (also: float4s per 4-row block)
#define SEQ   512
#define G3    (SEQ - 2) // 510
#define G4    (SEQ - 3) // 509
#define G5    (SEQ - 4) // 508
#define OFF4  125
#define OFF5  750       // 125 + 625
#define NT    512       // threads per block (8 waves)
#define RPB   4         // rows per block
#define BMS   128       // bitmap stride in words (122 used, padded)

typedef float floatx4 __attribute__((ext_vector_type(4)));

__global__ __launch_bounds__(NT) void ngram_bitmap4_kernel(
        const int* __restrict__ tokens,
        float* __restrict__ out) {
    __shared__ __align__(16) int tok[RPB * SEQ];       // 8 KB
    __shared__ unsigned int bm[RPB * BMS];             // 2 KB

    const int b   = blockIdx.x;
    const int tid = threadIdx.x;

    // --- stage 4 rows of tokens (1 int4/lane, coalesced) + zero bitmaps ---
    const int4* tsrc = (const int4*)(tokens + (size_t)b * (RPB * SEQ));
    ((int4*)tok)[tid] = tsrc[tid];                     // 512 * int4 = 2048 ints
    bm[tid] = 0u;                                      // RPB*BMS = 512 words
    __syncthreads();

    // --- scatter: 128 threads per row, 4 windows each, chained base-5 codes ---
    {
        const int row  = tid >> 7;                     // 0..3
        const int lane = tid & 127;
        const int* tr = tok + row * SEQ;
        unsigned int* bmr = bm + row * BMS;
        for (int i = lane; i < G3; i += 128) {
            const int r3 = tr[i] * 25 + tr[i + 1] * 5 + tr[i + 2];
            atomicOr(&bmr[r3 >> 5], 1u << (r3 & 31));
            if (i < G4) {
                const int r4 = r3 * 5 + tr[i + 3];
                const int v4 = OFF4 + r4;
                atomicOr(&bmr[v4 >> 5], 1u << (v4 & 31));
                if (i < G5) {
                    const int v5 = OFF5 + r4 * 5 + tr[i + 4];
                    atomicOr(&bmr[v5 >> 5], 1u << (v5 & 31));
                }
            }
        }
    }
    __syncthreads();

    // --- expand: 4*3875 dwords = exactly 3875 aligned float4 per block ---
    floatx4* ov = (floatx4*)(out + (size_t)b * (RPB * VOCAB));
    #pragma unroll 2
    for (int v = tid; v < VOCAB; v += NT) {
        floatx4 f;
        #pragma unroll
        for (int j = 0; j < 4; ++j) {
            const int d = 4 * v + j;
            const int r = d / VOCAB;                   // magic-mul, constant
            const int c = d - r * VOCAB;
            const unsigned int w = bm[r * BMS + (c >> 5)];
            f[j] = (float)((w >> (c & 31)) & 1u);
        }
        ov[v] = f;
    }
}

extern "C" void kernel_launch(void* const* d_in, const int* in_sizes, int n_in,
                              void* d_out, int out_size, void* d_ws, size_t ws_size,
                              hipStream_t stream) {
    const int* tokens = (const int*)d_in[0];
    float*     out    = (float*)d_out;
    // d_in[1] (`values`) is the vectorizer's ones payload — dead for the
    // binary presence output; not read.

    const int B = in_sizes[0] / SEQ;                   // 4096
    ngram_bitmap4_kernel<<<B / RPB, NT, 0, stream>>>(tokens, out);
}